// Round 6
// baseline (104.899 us; speedup 1.0000x reference)
//
#include <hip/hip_runtime.h>
#include <stdint.h>

typedef _Float16 f16x8 __attribute__((ext_vector_type(8)));
typedef float f32x4 __attribute__((ext_vector_type(4)));
typedef unsigned int u32x4 __attribute__((ext_vector_type(4)));

#define T_OBS 50
#define PRED 12

// ws layout (ushort == f16 bits):
//   enc frags: [t<8][kt<5][lane<64][j<8]   = 20480
//   dec frags: +20480
//   fc  frags: [kt<4][lane<64][j<8]        = 2048
#define DEC_OFF 20480
#define FC_OFF  40960
#define WS_ELEMS 43008

// kappa (physical A-column label) -> m (hidden-unit C/D-slot label)
// chosen so C/D slots feed B-frag slots with zero cross-lane movement.
// (Verified end-to-end in R1: passed, absmax 0.0078.)
__device__ __forceinline__ int unperm(int k) {
  return (k & 3) | (((k >> 3) & 3) << 2) | (((k >> 2) & 1) << 4) | (k & 0x60);
}

__global__ void prep_kernel(const float* __restrict__ Wih_e, const float* __restrict__ Whh_e,
                            const float* __restrict__ bih_e, const float* __restrict__ bhh_e,
                            const float* __restrict__ Wih_d, const float* __restrict__ Whh_d,
                            const float* __restrict__ bih_d, const float* __restrict__ bhh_d,
                            const float* __restrict__ fcW,
                            unsigned short* __restrict__ ws) {
  int idx = blockIdx.x * 256 + threadIdx.x;
  if (idx >= WS_ELEMS) return;
  float val = 0.0f;
  if (idx < FC_OFF) {
    const bool enc = idx < DEC_OFF;
    const int e = enc ? idx : idx - DEC_OFF;
    const int j = e & 7;
    const int lane = (e >> 3) & 63;
    const int rem = e >> 9;            // t*5 + kt
    const int kt = rem % 5;
    const int t = rem / 5;
    const int n = 16 * t + (lane & 15);
    const int kappa = 32 * kt + ((lane >> 4) << 3) + j;
    const float* Wih = enc ? Wih_e : Wih_d;
    const float* Whh = enc ? Whh_e : Whh_d;
    const float* bih = enc ? bih_e : bih_d;
    const float* bhh = enc ? bhh_e : bhh_d;
    if (kappa < 128)       val = Whh[n * 128 + unperm(kappa)];
    else if (kappa < 131)  val = Wih[n * 3 + (kappa - 128)];
    else if (kappa == 131) val = bih[n] + bhh[n];
    // kappa >= 132 -> 0 (padding)
  } else {
    const int e = idx - FC_OFF;
    const int j = e & 7;
    const int lane = (e >> 3) & 63;
    const int kt = e >> 9;             // 0..3 (h part only; fc bias added in VALU)
    const int o = lane & 15;
    const int kappa = 32 * kt + ((lane >> 4) << 3) + j;
    if (o < 3) val = fcW[o * 128 + unperm(kappa)];
  }
  _Float16 h = (_Float16)val;
  ws[idx] = __builtin_bit_cast(unsigned short, h);
}

__device__ __forceinline__ float tanh_fast(float v) {
  // tanh(v) = 1 - 2/(1 + e^{2v});  e^{2v} = exp2(v * 2*log2(e))
  float e = __builtin_amdgcn_exp2f(v * 2.8853900817779268f);
  return __builtin_fmaf(-2.0f, __builtin_amdgcn_rcpf(1.0f + e), 1.0f);
}

__device__ __forceinline__ unsigned int pk2(float a, float b) {
  return __builtin_bit_cast(unsigned int, __builtin_amdgcn_cvt_pkrtz(a, b));
}

__device__ __forceinline__ f16x8 ldfrag(const unsigned short* p) {
  return __builtin_bit_cast(f16x8, *(const u32x4*)p);
}

__device__ __forceinline__ f16x8 mkxf(float a, float b, float c) {
  // Only k-slots 0..3 (kappa 128..131, hi4==0 lanes) are nonzero in the A
  // x-tile; slots 4..7 MUST be zero-not-junk (junk f16 could be NaN; 0*NaN=NaN).
  u32x4 u;
  u[0] = pk2(a, b);
  u[1] = pk2(c, 1.0f);
  u[2] = 0u;
  u[3] = 0u;
  return __builtin_bit_cast(f16x8, u);
}

// One wave owns ALL of M (128 units) for TWO independent 16-seq streams.
// Zero barriers, zero LDS. Per step, source order MFMA(X); MFMA(Y); tanh(X);
// tanh(Y) lets X's tanh issue down the VALU pipe while Y's 40 MFMAs occupy the
// matrix pipe (disjoint registers -> no dependency). 256 blocks x 4 waves =
// 1024 waves = exactly 1 wave/SIMD, single batch; ~290 regs under the
// launch_bounds(256,1) cap of 512.
__global__ __launch_bounds__(256, 1) void traj_kernel(
    const float* __restrict__ src, const unsigned short* __restrict__ ws,
    const float* __restrict__ fcb, float* __restrict__ out) {
  const int lane = (int)(threadIdx.x & 63u);
  const int w = (int)(threadIdx.x >> 6u);
  const int sX = blockIdx.x * 128 + w * 32 + (lane & 15);  // stream X seq
  const int sY = sX + 16;                                   // stream Y seq
  const float* xpX = src + (size_t)(sX >> 6) * (T_OBS * 192) + (sX & 63) * 3;
  const float* xpY = src + (size_t)(sY >> 6) * (T_OBS * 192) + (sY & 63) * 3;

  // ---- encoder A-frags: all 8 m-tiles x 5 k-tiles (shared by both streams) ----
  f16x8 A[40];
  #pragma unroll
  for (int i = 0; i < 40; ++i)
    A[i] = ldfrag(ws + (size_t)(i * 64 + lane) * 8);

  f16x8 BfX[4], BfY[4];
  #pragma unroll
  for (int i = 0; i < 4; ++i) {
    u32x4 zz = (u32x4)0u;
    BfX[i] = __builtin_bit_cast(f16x8, zz);   // h0 = 0
    BfY[i] = __builtin_bit_cast(f16x8, zz);
  }
  f16x8 xfX = mkxf(xpX[0], xpX[1], xpX[2]);
  f16x8 xfY = mkxf(xpY[0], xpY[1], xpY[2]);

  const f32x4 z = (f32x4){0.f, 0.f, 0.f, 0.f};
  f32x4 aX[8], aY[8];

  // One RNN step for both streams. X's MFMAs issue first; Y's MFMAs (no deps
  // on X) keep the matrix pipe busy while X's tanh runs on the VALU pipe.
  auto rnn_step = [&]() {
    #pragma unroll
    for (int t = 0; t < 8; ++t) {
      aX[t] = __builtin_amdgcn_mfma_f32_16x16x32_f16(A[t * 5 + 4], xfX, z, 0, 0, 0);
      #pragma unroll
      for (int kt = 0; kt < 4; ++kt)
        aX[t] = __builtin_amdgcn_mfma_f32_16x16x32_f16(A[t * 5 + kt], BfX[kt], aX[t], 0, 0, 0);
    }
    #pragma unroll
    for (int t = 0; t < 8; ++t) {
      aY[t] = __builtin_amdgcn_mfma_f32_16x16x32_f16(A[t * 5 + 4], xfY, z, 0, 0, 0);
      #pragma unroll
      for (int kt = 0; kt < 4; ++kt)
        aY[t] = __builtin_amdgcn_mfma_f32_16x16x32_f16(A[t * 5 + kt], BfY[kt], aY[t], 0, 0, 0);
    }
    // tanh + pack straight into next step's B-frags (lane-local by the perm)
    #pragma unroll
    for (int kt = 0; kt < 4; ++kt) {
      u32x4 F;
      F[0] = pk2(tanh_fast(aX[2 * kt][0]),     tanh_fast(aX[2 * kt][1]));
      F[1] = pk2(tanh_fast(aX[2 * kt][2]),     tanh_fast(aX[2 * kt][3]));
      F[2] = pk2(tanh_fast(aX[2 * kt + 1][0]), tanh_fast(aX[2 * kt + 1][1]));
      F[3] = pk2(tanh_fast(aX[2 * kt + 1][2]), tanh_fast(aX[2 * kt + 1][3]));
      BfX[kt] = __builtin_bit_cast(f16x8, F);
    }
    #pragma unroll
    for (int kt = 0; kt < 4; ++kt) {
      u32x4 F;
      F[0] = pk2(tanh_fast(aY[2 * kt][0]),     tanh_fast(aY[2 * kt][1]));
      F[1] = pk2(tanh_fast(aY[2 * kt][2]),     tanh_fast(aY[2 * kt][3]));
      F[2] = pk2(tanh_fast(aY[2 * kt + 1][0]), tanh_fast(aY[2 * kt + 1][1]));
      F[3] = pk2(tanh_fast(aY[2 * kt + 1][2]), tanh_fast(aY[2 * kt + 1][3]));
      BfY[kt] = __builtin_bit_cast(f16x8, F);
    }
  };

  // ---- encoder: 50 steps, distance-1 x prefetch (clamped so xf ends = x[49]) ----
  for (int s = 0; s < T_OBS; ++s) {
    const int t2 = (s < T_OBS - 1) ? s + 1 : s;
    const float nX0 = xpX[t2 * 192], nX1 = xpX[t2 * 192 + 1], nX2 = xpX[t2 * 192 + 2];
    const float nY0 = xpY[t2 * 192], nY1 = xpY[t2 * 192 + 1], nY2 = xpY[t2 * 192 + 2];
    rnn_step();
    xfX = mkxf(nX0, nX1, nX2);
    xfY = mkxf(nY0, nY1, nY2);
  }

  // ---- decoder weights (in-place swap) + fc frags ----
  #pragma unroll
  for (int i = 0; i < 40; ++i)
    A[i] = ldfrag(ws + DEC_OFF + (size_t)(i * 64 + lane) * 8);
  f16x8 Afc[4];
  #pragma unroll
  for (int kt = 0; kt < 4; ++kt)
    Afc[kt] = ldfrag(ws + FC_OFF + (size_t)(kt * 64 + lane) * 8);
  const float fb0 = fcb[0], fb1 = fcb[1], fb2 = fcb[2];

  float* opX = out + (size_t)(sX >> 6) * (PRED * 192) + (sX & 63) * 3;
  float* opY = out + (size_t)(sY >> 6) * (PRED * 192) + (sY & 63) * 3;

  // ---- decoder: 12 autoregressive steps ----
  for (int p = 0; p < PRED; ++p) {
    rnn_step();
    // fc heads (K=128): output rows 0..2 land in pf[0..2] on lanes 0..15
    f32x4 pX = __builtin_amdgcn_mfma_f32_16x16x32_f16(Afc[0], BfX[0], z, 0, 0, 0);
    f32x4 pY = __builtin_amdgcn_mfma_f32_16x16x32_f16(Afc[0], BfY[0], z, 0, 0, 0);
    #pragma unroll
    for (int kt = 1; kt < 4; ++kt) {
      pX = __builtin_amdgcn_mfma_f32_16x16x32_f16(Afc[kt], BfX[kt], pX, 0, 0, 0);
      pY = __builtin_amdgcn_mfma_f32_16x16x32_f16(Afc[kt], BfY[kt], pY, 0, 0, 0);
    }
    const float pX0 = pX[0] + fb0, pX1 = pX[1] + fb1, pX2 = pX[2] + fb2;
    const float pY0 = pY[0] + fb0, pY1 = pY[1] + fb1, pY2 = pY[2] + fb2;
    if (lane < 16) {
      opX[p * 192 + 0] = pX0; opX[p * 192 + 1] = pX1; opX[p * 192 + 2] = pX2;
      opY[p * 192 + 0] = pY0; opY[p * 192 + 1] = pY1; opY[p * 192 + 2] = pY2;
    }
    // autoregressive feedback: preds live on lanes 0..15 == the lanes whose
    // xf k-slots are read (hi4==0); other lanes' values are finite and hit A=0.
    xfX = mkxf(pX0, pX1, pX2);
    xfY = mkxf(pY0, pY1, pY2);
  }
}

extern "C" void kernel_launch(void* const* d_in, const int* in_sizes, int n_in,
                              void* d_out, int out_size, void* d_ws, size_t ws_size,
                              hipStream_t stream) {
  const float* src   = (const float*)d_in[0];
  const float* Wih_e = (const float*)d_in[1];
  const float* Whh_e = (const float*)d_in[2];
  const float* bih_e = (const float*)d_in[3];
  const float* bhh_e = (const float*)d_in[4];
  const float* Wih_d = (const float*)d_in[5];
  const float* Whh_d = (const float*)d_in[6];
  const float* bih_d = (const float*)d_in[7];
  const float* bhh_d = (const float*)d_in[8];
  const float* fcW   = (const float*)d_in[9];
  const float* fcb   = (const float*)d_in[10];
  (void)in_sizes; (void)n_in; (void)out_size; (void)ws_size;

  unsigned short* ws = (unsigned short*)d_ws;

  prep_kernel<<<(WS_ELEMS + 255) / 256, 256, 0, stream>>>(
      Wih_e, Whh_e, bih_e, bhh_e, Wih_d, Whh_d, bih_d, bhh_d, fcW, ws);

  // 32768 seqs / 32 per wave (2 independent 16-seq streams) / 4 waves = 256 blocks
  traj_kernel<<<256, 256, 0, stream>>>(src, ws, fcb, (float*)d_out);
}